// Round 9
// baseline (249.465 us; speedup 1.0000x reference)
//
#include <hip/hip_runtime.h>

typedef unsigned short u16;
typedef short bf16x8 __attribute__((ext_vector_type(8)));
typedef float f32x4 __attribute__((ext_vector_type(4)));
typedef const __attribute__((address_space(1))) void* gptr_t;
typedef __attribute__((address_space(3))) void* lptr_t;

#define B_   64
#define N_   393
#define C_   768
#define H_   12
#define HD_  64
#define P_   197
#define BIAS_N 416
#define PPAD 208
#define VTP  448
#define M_KV (B_ * N_)   // 25152
#define M_PR (B_ * P_)   // 12608
#define SCALE_L2E 0.180336879f   // 0.125 * log2(e)

__device__ __forceinline__ u16 f2bf(float f) {
    unsigned u = __float_as_uint(f);
    return (u16)((u + 0x7FFFu + ((u >> 16) & 1u)) >> 16);
}
__device__ __forceinline__ unsigned cvt_pk_bf16(float lo, float hi) {
    unsigned r;
    asm("v_cvt_pk_bf16_f32 %0, %1, %2" : "=v"(r) : "v"(lo), "v"(hi));
    return r;
}
__device__ __forceinline__ float exp2_fast(float x) {
    float r;
    asm("v_exp_f32 %0, %1" : "=v"(r) : "v"(x));
    return r;
}

// ---------------------------------------------------------------------------
// conv_all: fused fp32->bf16 for x, wk, wv, proj_w (one launch)
// ---------------------------------------------------------------------------
__global__ __launch_bounds__(256) void conv_all(
    const float* __restrict__ x, const float* __restrict__ wk,
    const float* __restrict__ wv, const float* __restrict__ pw,
    u16* __restrict__ xh, u16* __restrict__ wkvh, u16* __restrict__ pwh)
{
    const int XN4 = 19316736 / 4;
    const int WN4 = 589824 / 4;
    int i = blockIdx.x * 256 + threadIdx.x;
    const float* src; u16* dst; int off;
    if (i < XN4) { src = x; dst = xh; off = i; }
    else {
        int j = i - XN4;
        int sec = j / WN4;
        off = j - sec * WN4;
        src = sec == 0 ? wk : (sec == 1 ? wv : pw);
        dst = sec == 0 ? wkvh : (sec == 1 ? wkvh + 589824 : pwh);
    }
    float4 v = ((const float4*)src)[off];
    u16 o[4] = {f2bf(v.x), f2bf(v.y), f2bf(v.z), f2bf(v.w)};
    *(uint2*)(dst + off * 4) = *(uint2*)o;
}

// ---------------------------------------------------------------------------
// prep1 / prep2 (unchanged)
// ---------------------------------------------------------------------------
__global__ __launch_bounds__(256) void prep1_kernel(
    const float* __restrict__ q_learned, const float* __restrict__ pos_embed,
    const float* __restrict__ rpe_w, u16* __restrict__ qh, float* __restrict__ lk)
{
    __shared__ float q_s[C_];
    const int p = blockIdx.x, t = threadIdx.x;
    for (int c = t; c < C_; c += 256) {
        float v = q_learned[c] + pos_embed[p * C_ + c];
        q_s[c] = v;
        qh[p * C_ + c] = f2bf(v);
    }
    __syncthreads();
    if (t < H_ * 8) {
        int h = t >> 3, u = t & 7;
        float s = 0.f;
        #pragma unroll 8
        for (int d = 0; d < HD_; ++d)
            s = fmaf(q_s[h * HD_ + d], rpe_w[d * 8 + u], s);
        lk[(h * P_ + p) * 8 + u] = s;
    }
}

__global__ __launch_bounds__(256) void prep2_kernel(
    const float* __restrict__ lk, const int* __restrict__ rp_bucket,
    float* __restrict__ biasT)
{
    int bx = blockIdx.x;
    int h = bx / N_, j = bx % N_;
    int t = threadIdx.x;
    if (t >= PPAD) return;
    int jm;
    if (j == 0) jm = 0;
    else { jm = j - 1; if (jm >= 196) jm -= 196; jm += 1; }
    float v = 0.f;
    if (t < P_) {
        int bucket = rp_bucket[t * P_ + jm];
        v = lk[(h * P_ + t) * 8 + bucket] * 1.44269504f;
    }
    biasT[((size_t)h * BIAS_N + j) * PPAD + t] = v;
}

// ---------------------------------------------------------------------------
// gemm_kv8: 256x256x(BK=64) 8-phase counted-vmcnt pipeline (T3+T4).
// 512 thr = 8 waves (2M x 4N); per-wave 128x64 out (acc[8][4]).
// LDS 128KB: unit = (X in {A,B}, dbuf, kappa k-half) 256 rows x 32 k bf16.
// Phase = (K-tile quadrant): 8 swz ds_read_b128 + 1 unit staged (2 gload_lds)
//         + vmcnt(lit) + s_barrier + lgkmcnt(0)+sched_barrier + 16 MFMA + s_barrier.
// Ledger: stage targets region last-read <= prev phase (WAR safe via end
// barrier); first read >= 5 phases after issue; vmcnt(8)+mid-barrier makes
// cross-wave landing safe at depth 4. Chunk swizzle: pi(row)=row^((row>>2)&1),
// slot^=row&3 (bijective; 2-way banks = free). Epilogue vmcnt 6/4/2/0.
// ---------------------------------------------------------------------------
__global__ __launch_bounds__(512, 1) void gemm_kv8(
    const u16* __restrict__ A, const u16* __restrict__ Bw, u16* __restrict__ KV)
{
    __shared__ __align__(16) u16 lds[65536];   // 128 KB: A units [0,32768), B [32768,65536)

    const int nwg = 6 * 99;
    const int orig = blockIdx.y * 6 + blockIdx.x;
    const int xcd = orig & 7, rank = orig >> 3;
    const int q = nwg >> 3, r = nwg & 7;
    const int wgid = (xcd < r ? xcd * (q + 1) : r * (q + 1) + (xcd - r) * q) + rank;
    const int n0 = (wgid % 6) * 256;
    const int m0 = (wgid / 6) * 256;

    const int t = threadIdx.x;
    const int wid = t >> 6, l = t & 63;
    const int wr = wid >> 2, wc = wid & 3;
    const int l15 = l & 15, lg = l >> 4;
    const int Mc = M_KV - 1;

    // staging source bases for chunk0 (c=t) and chunk1 (c=t+512)
    const u16* gA[2]; const u16* gB[2];
    #pragma unroll
    for (int i = 0; i < 2; ++i) {
        int c = t + 512 * i;
        int prow = c >> 2, s = c & 3;
        int row = prow ^ ((prow >> 2) & 1);
        int slot = s ^ (row & 3);
        int arow = m0 + row; if (arow > Mc) arow = Mc;
        gA[i] = A + (size_t)arow * 768 + slot * 8;
        gB[i] = Bw + (size_t)(n0 + row) * 768 + slot * 8;
    }

    // swizzled ds_read chunk offsets (u16 units): chunk = pi(r)*4 + (lg^(r&3))
    int au[8], bu[4];
    #pragma unroll
    for (int mf = 0; mf < 8; ++mf) {
        int rowu = wr * 128 + mf * 16 + l15;
        au[mf] = ((rowu ^ ((rowu >> 2) & 1)) * 4 + (lg ^ (rowu & 3))) * 8;
    }
    #pragma unroll
    for (int nf = 0; nf < 4; ++nf) {
        int colu = wc * 64 + nf * 16 + l15;
        bu[nf] = ((colu ^ ((colu >> 2) & 1)) * 4 + (lg ^ (colu & 3))) * 8;
    }

    f32x4 acc[8][4];
    #pragma unroll
    for (int i = 0; i < 8; ++i)
        #pragma unroll
        for (int j = 0; j < 4; ++j) acc[i][j] = (f32x4){0.f, 0.f, 0.f, 0.f};

#define STAGE_UNIT(XSEL, KT, KAP) do {                                          \
    unsigned _lb = ((XSEL) ? 32768u : 0u) +                                     \
                   (unsigned)(((((KT) & 1) * 2 + (KAP)) * 8192));               \
    const u16* _g0 = (XSEL) ? gB[0] : gA[0];                                    \
    const u16* _g1 = (XSEL) ? gB[1] : gA[1];                                    \
    __builtin_amdgcn_global_load_lds((gptr_t)(const void*)(_g0 + (KT)*64 + (KAP)*32), \
        (lptr_t)(void*)(lds + _lb + (unsigned)t * 8), 16, 0, 0);                \
    __builtin_amdgcn_global_load_lds((gptr_t)(const void*)(_g1 + (KT)*64 + (KAP)*32), \
        (lptr_t)(void*)(lds + _lb + (unsigned)(t + 512) * 8), 16, 0, 0);        \
} while (0)

#define QPHASE(KT, Q, VMLIT, DOSTG, SX, SKT, SKAP) do {                         \
    const int _db = (KT) & 1;                                                   \
    const int _kap = (Q) >> 1;                                                  \
    const int _mh = (Q) & 1;                                                    \
    const unsigned _ab = (unsigned)((_db * 2 + _kap) * 8192);                   \
    const unsigned _bb = 32768u + _ab;                                          \
    bf16x8 _af[4], _bf[4];                                                      \
    _Pragma("unroll") for (int _j = 0; _j < 4; ++_j) {                          \
        _af[_j] = *(const bf16x8*)(lds + _ab + au[_mh * 4 + _j]);               \
        _bf[_j] = *(const bf16x8*)(lds + _bb + bu[_j]); }                       \
    if (DOSTG) STAGE_UNIT(SX, SKT, SKAP);                                       \
    asm volatile("s_waitcnt vmcnt(" #VMLIT ")" ::: "memory");                   \
    __builtin_amdgcn_s_barrier();                                               \
    asm volatile("s_waitcnt lgkmcnt(0)" ::: "memory");                          \
    __builtin_amdgcn_sched_barrier(0);                                          \
    __builtin_amdgcn_s_setprio(1);                                              \
    _Pragma("unroll") for (int _j = 0; _j < 4; ++_j)                            \
        _Pragma("unroll") for (int _nf = 0; _nf < 4; ++_nf)                     \
            acc[_mh * 4 + _j][_nf] = __builtin_amdgcn_mfma_f32_16x16x32_bf16(   \
                _af[_j], _bf[_nf], acc[_mh * 4 + _j][_nf], 0, 0, 0);            \
    __builtin_amdgcn_s_setprio(0);                                              \
    __builtin_amdgcn_s_barrier();                                               \
} while (0)

    // prologue: tiles 0,1 (8 units, issue order = ledger positions 1..8)
    STAGE_UNIT(0, 0, 0); STAGE_UNIT(1, 0, 0);
    STAGE_UNIT(0, 0, 1); STAGE_UNIT(1, 0, 1);
    STAGE_UNIT(0, 1, 0); STAGE_UNIT(1, 1, 0);
    STAGE_UNIT(0, 1, 1); STAGE_UNIT(1, 1, 1);
    asm volatile("s_waitcnt vmcnt(12)" ::: "memory");
    __builtin_amdgcn_s_barrier();

    // iteration 0  (G=1..8)
    QPHASE(0, 0, 12, 0, 0, 0, 0);
    QPHASE(0, 1, 8,  0, 0, 0, 0);
    QPHASE(0, 2, 8,  1, 0, 2, 0);
    QPHASE(0, 3, 8,  1, 1, 2, 0);
    QPHASE(1, 0, 8,  1, 0, 2, 1);
    QPHASE(1, 1, 8,  1, 1, 2, 1);
    QPHASE(1, 2, 8,  1, 0, 3, 0);
    QPHASE(1, 3, 8,  1, 1, 3, 0);
    // iterations 1..4 (steady state)
    for (int it = 1; it <= 4; ++it) {
        const int kt0 = 2 * it, kt1 = 2 * it + 1;
        QPHASE(kt0, 0, 8, 1, 0, kt1,     1);
        QPHASE(kt0, 1, 8, 1, 1, kt1,     1);
        QPHASE(kt0, 2, 8, 1, 0, kt0 + 2, 0);
        QPHASE(kt0, 3, 8, 1, 1, kt0 + 2, 0);
        QPHASE(kt1, 0, 8, 1, 0, kt0 + 2, 1);
        QPHASE(kt1, 1, 8, 1, 1, kt0 + 2, 1);
        QPHASE(kt1, 2, 8, 1, 0, kt1 + 2, 0);
        QPHASE(kt1, 3, 8, 1, 1, kt1 + 2, 0);
    }
    // iteration 5 (G=41..48, epilogue vmcnt ramp-down)
    QPHASE(10, 0, 8, 1, 0, 11, 1);
    QPHASE(10, 1, 8, 1, 1, 11, 1);
    QPHASE(10, 2, 6, 0, 0, 0, 0);
    QPHASE(10, 3, 4, 0, 0, 0, 0);
    QPHASE(11, 0, 2, 0, 0, 0, 0);
    QPHASE(11, 1, 0, 0, 0, 0, 0);
    QPHASE(11, 2, 0, 0, 0, 0, 0);
    QPHASE(11, 3, 0, 0, 0, 0, 0);

#undef QPHASE
#undef STAGE_UNIT

    // epilogue: coalesced bf16 stores
    #pragma unroll
    for (int mf = 0; mf < 8; ++mf)
        #pragma unroll
        for (int nf = 0; nf < 4; ++nf) {
            int col = n0 + wc * 64 + nf * 16 + l15;
            #pragma unroll
            for (int rr = 0; rr < 4; ++rr) {
                int m = m0 + wr * 128 + mf * 16 + lg * 4 + rr;
                if (m < M_KV) KV[(size_t)m * 1536 + col] = f2bf(acc[mf][nf][rr]);
            }
        }
}

// ---------------------------------------------------------------------------
// proj GEMM: m97 structure (unchanged, known-good)
// ---------------------------------------------------------------------------
__global__ __launch_bounds__(256) void gemm_proj(
    const u16* __restrict__ A, const u16* __restrict__ Bw,
    float* __restrict__ Cf, const float* __restrict__ bias)
{
    __shared__ __align__(16) u16 As[128 * 64];
    __shared__ __align__(16) u16 Bs[128 * 64];

    const int gx = gridDim.x;
    const int nwg = gx * gridDim.y;
    const int orig = blockIdx.y * gx + blockIdx.x;
    const int xcd = orig & 7, rank = orig >> 3;
    const int q = nwg >> 3, r = nwg & 7;
    const int wgid = (xcd < r ? xcd * (q + 1) : r * (q + 1) + (xcd - r) * q) + rank;
    const int n0 = (wgid % gx) * 128;
    const int m0 = (wgid / gx) * 128;

    const int t = threadIdx.x;
    const int w = t >> 6, l = t & 63;
    const int wr = w >> 1, wc = w & 1;
    const int l15 = l & 15, lg = l >> 4;
    const int lrow = l >> 3, lslot = l & 7;
    const int Mc = M_PR - 1;

    f32x4 acc[4][4];
    #pragma unroll
    for (int i = 0; i < 4; ++i)
        #pragma unroll
        for (int j = 0; j < 4; ++j) acc[i][j] = (f32x4){0.f, 0.f, 0.f, 0.f};

    for (int ks = 0; ks < 12; ++ks) {
        const int k0 = ks * 64;
        if (ks) __syncthreads();
        #pragma unroll
        for (int i = 0; i < 4; ++i) {
            const int rbase = w * 32 + i * 8;
            int arow = m0 + rbase + lrow; if (arow > Mc) arow = Mc;
            const int brow = n0 + rbase + lrow;
            const u16* ga = A  + (size_t)arow * 768 + k0 + lslot * 8;
            const u16* gb = Bw + (size_t)brow * 768 + k0 + lslot * 8;
            __builtin_amdgcn_global_load_lds((gptr_t)(const void*)ga,
                                             (lptr_t)(void*)(As + rbase * 64), 16, 0, 0);
            __builtin_amdgcn_global_load_lds((gptr_t)(const void*)gb,
                                             (lptr_t)(void*)(Bs + rbase * 64), 16, 0, 0);
        }
        __syncthreads();
        #pragma unroll
        for (int kk = 0; kk < 2; ++kk) {
            bf16x8 af[4], bfr[4];
            #pragma unroll
            for (int mf = 0; mf < 4; ++mf) {
                af[mf]  = *(const bf16x8*)(As + (wr * 64 + mf * 16 + l15) * 64 + (kk * 4 + lg) * 8);
                bfr[mf] = *(const bf16x8*)(Bs + (wc * 64 + mf * 16 + l15) * 64 + (kk * 4 + lg) * 8);
            }
            #pragma unroll
            for (int mf = 0; mf < 4; ++mf)
                #pragma unroll
                for (int nf = 0; nf < 4; ++nf)
                    acc[mf][nf] = __builtin_amdgcn_mfma_f32_16x16x32_bf16(
                        af[mf], bfr[nf], acc[mf][nf], 0, 0, 0);
        }
    }

    #pragma unroll
    for (int mf = 0; mf < 4; ++mf)
        #pragma unroll
        for (int nf = 0; nf < 4; ++nf) {
            int col = n0 + wc * 64 + nf * 16 + l15;
            float bb = bias[col];
            #pragma unroll
            for (int rr = 0; rr < 4; ++rr) {
                int m = m0 + wr * 64 + mf * 16 + lg * 4 + rr;
                if (m < M_PR) Cf[(size_t)m * 768 + col] = acc[mf][nf][rr] + bb;
            }
        }
}

// ---------------------------------------------------------------------------
// vtrans (unchanged)
// ---------------------------------------------------------------------------
__global__ __launch_bounds__(256) void vtrans_kernel(const u16* __restrict__ KV,
                                                     u16* __restrict__ Vt)
{
    const int bh = blockIdx.x;
    const int b = bh / H_, h = bh % H_;
    const int t = threadIdx.x, w = t >> 6, l = t & 63;
    const int d = w * 16 + (l >> 2);
    const int c = l & 3;
    const u16* src = KV + (size_t)b * N_ * 1536 + 768 + h * HD_ + d;
    u16* dst = Vt + (size_t)(bh * HD_ + d) * VTP;
    for (int jb = 0; jb < VTP; jb += 32) {
        int j0 = jb + c * 8;
        u16 v[8];
        #pragma unroll
        for (int i = 0; i < 8; ++i) {
            int j = j0 + i;
            v[i] = (j < N_) ? src[(size_t)j * 1536] : (u16)0;
        }
        *(bf16x8*)(dst + j0) = *(bf16x8*)v;
    }
}

// ---------------------------------------------------------------------------
// attention v5: r8 structure + N-tail trim (tile 6: sub0 only in QK^T/softmax,
// kc0-only PV; P cols 400-415 zero-filled; cols 416-447 never read).
// ---------------------------------------------------------------------------
__global__ __launch_bounds__(256, 2) void attn_mfma5(
    const u16* __restrict__ qh, const u16* __restrict__ KV,
    const u16* __restrict__ Vt, const float* __restrict__ biasT,
    u16* __restrict__ Obuf)
{
    __shared__ __align__(16) u16 pts[64 * 456];
    __shared__ __align__(16) u16 kvs[2][64 * 64];

    const int id = blockIdx.x;
    const int work = (id & 7) * 384 + (id >> 3);
    const int ptile = work & 3;
    const int rest = work >> 2;
    const int h = rest % 12;
    const int b = rest / 12;
    const int p0 = ptile * 64;

    const int t = threadIdx.x, w = t >> 6, l = t & 63;
    const int l15 = l & 15, lg = l >> 4;
    const int p0w = p0 + w * 16;

    int srow[2], sslot[2], swoff[2];
    #pragma unroll
    for (int i = 0; i < 2; ++i) {
        int c = t + 256 * i;
        srow[i] = c >> 3; sslot[i] = c & 7;
        swoff[i] = srow[i] * 64 + ((sslot[i] ^ (srow[i] & 7)) << 3);
    }

    int prow = p0w + l15; if (prow > P_ - 1) prow = P_ - 1;
    const u16* qp = qh + (size_t)prow * C_ + h * HD_ + lg * 8;
    bf16x8 qf0 = *(const bf16x8*)(qp);
    bf16x8 qf1 = *(const bf16x8*)(qp + 32);

    const u16* Kbase = KV + (size_t)b * (N_ * 1536) + h * HD_;
    const u16* Vbase = Vt + (size_t)(b * H_ + h) * (HD_ * VTP);

    f32x4 acc[7][4];
    #pragma unroll
    for (int i = 0; i < 7; ++i)
        #pragma unroll
        for (int j = 0; j < 4; ++j) acc[i][j] = (f32x4){0.f, 0.f, 0.f, 0.f};

    // ---------------- pass 1: QK^T ----------------
    bf16x8 ra[2];
    #pragma unroll
    for (int i = 0; i < 2; ++i)
        ra[i] = *(const bf16x8*)(Kbase + (size_t)srow[i] * 1536 + sslot[i] * 8);
    #pragma unroll
    for (int i = 0; i < 2; ++i) *(bf16x8*)(&kvs[0][swoff[i]]) = ra[i];
    __syncthreads();

    #pragma unroll
    for (int nt = 0; nt < 7; ++nt) {
        const u16* kcur = kvs[nt & 1];
        if (nt < 6) {
            #pragma unroll
            for (int i = 0; i < 2; ++i) {
                int rn = (nt + 1) * 64 + srow[i]; if (rn > N_ - 1) rn = N_ - 1;
                ra[i] = *(const bf16x8*)(Kbase + (size_t)rn * 1536 + sslot[i] * 8);
            }
        }
        const int smax = (nt == 6) ? 1 : 4;
        __builtin_amdgcn_s_setprio(1);
        #pragma unroll
        for (int kc = 0; kc < 2; ++kc)
            #pragma unroll
            for (int sub = 0; sub < smax; ++sub) {
                int row = sub * 16 + l15;
                bf16x8 kb = *(const bf16x8*)(kcur + row * 64 + (((kc * 4 + lg) ^ (row & 7)) << 3));
                acc[nt][sub] = __builtin_amdgcn_mfma_f32_16x16x32_bf16(
                    kc ? qf1 : qf0, kb, acc[nt][sub], 0, 0, 0);
            }
        __builtin_amdgcn_s_setprio(0);
        if (nt < 6) {
            #pragma unroll
            for (int i = 0; i < 2; ++i) *(bf16x8*)(&kvs[(nt + 1) & 1][swoff[i]]) = ra[i];
        }
        __syncthreads();
    }

    // issue V tile 0 loads; softmax hides latency (T14)
    #pragma unroll
    for (int i = 0; i < 2; ++i)
        ra[i] = *(const bf16x8*)(Vbase + (size_t)srow[i] * VTP + sslot[i] * 8);

    // ---------------- single-pass softmax ----------------
    const int pcl = (p0w + lg * 4) > (PPAD - 4) ? (PPAD - 4) : (p0w + lg * 4);
    float s4[4] = {0.f, 0.f, 0.f, 0.f};
    #pragma unroll
    for (int nt = 0; nt < 7; ++nt) {
        const int smax = (nt == 6) ? 1 : 4;
        #pragma unroll
        for (int sub = 0; sub < smax; ++sub) {
            int n = nt * 64 + sub * 16 + l15;
            if (n < N_) {
                float4 b4 = *(const float4*)(biasT + ((size_t)h * BIAS_N + n) * PPAD + pcl);
                float bb[4] = {b4.x, b4.y, b4.z, b4.w};
                #pragma unroll
                for (int rr = 0; rr < 4; ++rr) {
                    float e = exp2_fast(fmaf(acc[nt][sub][rr], SCALE_L2E, bb[rr]));
                    acc[nt][sub][rr] = e;
                    s4[rr] += e;
                }
            } else {
                acc[nt][sub] = (f32x4){0.f, 0.f, 0.f, 0.f};
            }
        }
    }
    float rinv4[4];
    #pragma unroll
    for (int rr = 0; rr < 4; ++rr) {
        float s = s4[rr];
        s += __shfl_xor(s, 1); s += __shfl_xor(s, 2);
        s += __shfl_xor(s, 4); s += __shfl_xor(s, 8);
        rinv4[rr] = 1.0f / s;
    }

    // ---------------- P (unnormalized) -> LDS bf16 ----------------
    {
        const int rowb = w * 16 + lg * 4;
        #pragma unroll
        for (int nt = 0; nt < 7; ++nt) {
            const int smax = (nt == 6) ? 1 : 4;
            #pragma unroll
            for (int sub = 0; sub < smax; ++sub) {
                int col = nt * 64 + sub * 16 + l15;
                unsigned pk01 = cvt_pk_bf16(acc[nt][sub][0], acc[nt][sub][1]);
                unsigned pk23 = cvt_pk_bf16(acc[nt][sub][2], acc[nt][sub][3]);
                pts[(rowb + 0) * 456 + col] = (u16)pk01;
                pts[(rowb + 1) * 456 + col] = (u16)(pk01 >> 16);
                pts[(rowb + 2) * 456 + col] = (u16)pk23;
                pts[(rowb + 3) * 456 + col] = (u16)(pk23 >> 16);
            }
        }
        // zero P cols 400-415 (read by PV tail kc0); 416-447 never read
        #pragma unroll
        for (int rr = 0; rr < 4; ++rr)
            pts[(rowb + rr) * 456 + 400 + l15] = 0;
    }
    #pragma unroll
    for (int i = 0; i < 2; ++i) *(bf16x8*)(&kvs[0][swoff[i]]) = ra[i];
    __syncthreads();

    // ---------------- pass 2: PV ----------------
    f32x4 o[4];
    #pragma unroll
    for (int i = 0; i < 4; ++i) o[i] = (f32x4){0.f, 0.f, 0.f, 0.f};

    #pragma unroll
    for (int nt = 0; nt < 7; ++nt) {
        const u16* kcur = kvs[nt & 1];
        if (nt < 6) {
            #pragma unroll
            for (int i = 0; i < 2; ++i)
                ra[i] = *(const bf16x8*)(Vbase + (size_t)srow[i] * VTP + (nt + 1) * 64 + sslot[i] * 8);
        }
        const int kcmax = (nt == 6) ? 1 : 2;
        __builtin_amdgcn_s_setprio(1);
        #pragma unroll
        for (int kc = 0; kc < kcmax; ++kc) {
            bf16x8 pa = *(const bf16x8*)(pts + (w * 16 + l15) * 456 + nt * 64 + kc * 32 + lg * 8);
            #pragma unroll
            for (int dsub = 0; dsub < 4; ++dsub) {
                int row = dsub * 16 + l15;
                bf16x8 vb = *(const bf16x8*)(kcur + row * 64 + (((kc * 4 + lg) ^ (row & 7)) << 3));
                o[dsub] = __builtin_amdgcn_mfma_f32_16x16x32_bf16(pa, vb, o[dsub], 0, 0, 0);
            }
        }
        __builtin_amdgcn_s_setprio(0);
        if (nt < 6) {
            #pragma unroll
            for (int i = 0; i < 2; ++i) *(bf16x8*)(&kvs[(nt + 1) & 1][swoff[i]]) = ra[i];
        }
        __syncthreads();
    }

    // ---------------- store (normalize here) ----------------
    #pragma unroll
    for (int dsub = 0; dsub < 4; ++dsub)
        #pragma unroll
        for (int rr = 0; rr < 4; ++rr) {
            int p = p0w + lg * 4 + rr;
            if (p < P_)
                Obuf[((size_t)b * P_ + p) * C_ + h * HD_ + dsub * 16 + l15] =
                    f2bf(o[dsub][rr] * rinv4[rr]);
        }
}

// ---------------------------------------------------------------------------
extern "C" void kernel_launch(void* const* d_in, const int* in_sizes, int n_in,
                              void* d_out, int out_size, void* d_ws, size_t ws_size,
                              hipStream_t stream)
{
    const float* x         = (const float*)d_in[0];
    const float* q_learned = (const float*)d_in[1];
    const float* pos_embed = (const float*)d_in[2];
    const float* wk        = (const float*)d_in[3];
    const float* wv        = (const float*)d_in[4];
    const float* rpe_w     = (const float*)d_in[5];
    const float* proj_w    = (const float*)d_in[6];
    const float* proj_b    = (const float*)d_in[7];
    const int*   rp_bucket = (const int*)d_in[8];
    float* out = (float*)d_out;

    char* ws = (char*)d_ws;
    u16*   xh    = (u16*)(ws);                        // 38,633,472 B
    u16*   wkvh  = (u16*)(ws + 38633472);             //  2,359,296 B
    u16*   pwh   = (u16*)(ws + 40992768);             //  1,179,648 B
    u16*   qh    = (u16*)(ws + 42172416);             //    302,592 B
    float* lk    = (float*)(ws + 42475008);           //     75,776 B
    float* biasT = (float*)(ws + 42550784);           //  4,153,344 B
    u16*   KV    = (u16*)(ws + 46704128);             // 77,266,944 B
    u16*   Vt    = (u16*)(ws + 123971072);            // 44,040,192 B
    u16*   Obuf  = (u16*)(ws + 168011264);            // 19,365,888 B

    conv_all<<<20592, 256, 0, stream>>>(x, wk, wv, proj_w, xh, wkvh, pwh);

    prep1_kernel<<<P_, 256, 0, stream>>>(q_learned, pos_embed, rpe_w, qh, lk);
    prep2_kernel<<<H_ * N_, 256, 0, stream>>>(lk, rp_bucket, biasT);

    dim3 gkv(6, 99);    // 256x256 tiles: N=1536/256, M=ceil(25152/256)
    gemm_kv8<<<gkv, 512, 0, stream>>>(xh, wkvh, KV);

    vtrans_kernel<<<B_ * H_, 256, 0, stream>>>(KV, Vt);

    attn_mfma5<<<3072, 256, 0, stream>>>(qh, KV, Vt, biasT, Obuf);

    dim3 gpr(768 / 128, (M_PR + 127) / 128);
    gemm_proj<<<gpr, 256, 0, stream>>>(Obuf, pwh, out, proj_b);
}